// Round 1
// baseline (192.286 us; speedup 1.0000x reference)
//
#include <hip/hip_runtime.h>
#include <math.h>

#define HIDDEN 1024
#define SEQ 32768

// One 64-lane wave per row: lane loads 4x float4 (16 floats), FMA with hidden,
// wave shuffle-reduce -> energies[row].
__global__ __launch_bounds__(256) void energies_kernel(
    const float* __restrict__ hidden,
    const float* __restrict__ enc,
    float* __restrict__ energies) {
    const int lane = threadIdx.x & 63;
    const int wave = threadIdx.x >> 6;
    const int row  = blockIdx.x * 4 + wave;

    const float4* __restrict__ rowp = (const float4*)(enc + (size_t)row * HIDDEN);
    const float4* __restrict__ hp   = (const float4*)hidden;

    float acc = 0.f;
#pragma unroll
    for (int i = 0; i < 4; ++i) {
        float4 a = rowp[lane + i * 64];
        float4 h = hp[lane + i * 64];
        acc += a.x * h.x + a.y * h.y + a.z * h.z + a.w * h.w;
    }
#pragma unroll
    for (int off = 32; off > 0; off >>= 1)
        acc += __shfl_down(acc, off, 64);
    if (lane == 0) energies[row] = acc;
}

// Single block, 1024 threads, 32 energies/thread held in registers.
// max-reduce -> exp & sum-reduce -> normalize, all in-place on `buf`.
__global__ __launch_bounds__(1024) void softmax_kernel(float* __restrict__ buf) {
    __shared__ float red[16];
    const int tid  = threadIdx.x;
    const int lane = tid & 63;
    const int wv   = tid >> 6;

    float e[32];
    float m = -INFINITY;
#pragma unroll
    for (int i = 0; i < 32; ++i) {
        e[i] = buf[tid + i * 1024];
        m = fmaxf(m, e[i]);
    }
#pragma unroll
    for (int off = 32; off > 0; off >>= 1)
        m = fmaxf(m, __shfl_down(m, off, 64));
    if (lane == 0) red[wv] = m;
    __syncthreads();
    if (tid < 16) {
        float v = red[tid];
#pragma unroll
        for (int off = 8; off > 0; off >>= 1)
            v = fmaxf(v, __shfl_down(v, off, 64));
        if (tid == 0) red[0] = v;
    }
    __syncthreads();
    m = red[0];
    __syncthreads();  // everyone has read red[0] before it is overwritten below

    float s = 0.f;
#pragma unroll
    for (int i = 0; i < 32; ++i) {
        e[i] = __expf(e[i] - m);
        s += e[i];
    }
#pragma unroll
    for (int off = 32; off > 0; off >>= 1)
        s += __shfl_down(s, off, 64);
    if (lane == 0) red[wv] = s;
    __syncthreads();
    if (tid < 16) {
        float v = red[tid];
#pragma unroll
        for (int off = 8; off > 0; off >>= 1)
            v += __shfl_down(v, off, 64);
        if (tid == 0) red[0] = v;
    }
    __syncthreads();
    const float inv = 1.f / red[0];
#pragma unroll
    for (int i = 0; i < 32; ++i)
        buf[tid + i * 1024] = e[i] * inv;
}

extern "C" void kernel_launch(void* const* d_in, const int* in_sizes, int n_in,
                              void* d_out, int out_size, void* d_ws, size_t ws_size,
                              hipStream_t stream) {
    const float* hidden = (const float*)d_in[0];           // [1024]
    const float* enc    = (const float*)d_in[1];           // [32768, 1024]
    float* out = (float*)d_out;                            // [32768] == energies staging

    // Stage energies directly in d_out (exact size match), then softmax in-place.
    energies_kernel<<<SEQ / 4, 256, 0, stream>>>(hidden, enc, out);
    softmax_kernel<<<1, 1024, 0, stream>>>(out);
}